// Round 5
// baseline (484.349 us; speedup 1.0000x reference)
//
#include <hip/hip_runtime.h>
#include <hip/hip_bf16.h>
#include <stdint.h>

typedef __bf16 bf16_t;
typedef __bf16 bf16x8 __attribute__((ext_vector_type(8)));
typedef __bf16 bf16x4 __attribute__((ext_vector_type(4)));
typedef float f32x4 __attribute__((ext_vector_type(4)));

template <int V> struct ic { static constexpr int value = V; };

// async global->LDS, 16B per lane. LDS dest must be wave-uniform base + lane*16;
// the GLOBAL source is per-lane (used below to fold the frag-pack permutation
// into the staging itself).
__device__ __forceinline__ void gload_lds16(const bf16_t* g, bf16_t* l) {
  __builtin_amdgcn_global_load_lds((const __attribute__((address_space(1))) void*)g,
                                   (__attribute__((address_space(3))) void*)l, 16, 0, 0);
}

// ---------------- fp32 W[k][m] -> bf16 Bt[m][k] (tiled transpose + cast) --------
__global__ __launch_bounds__(256) void transpose_cast_k(const float* __restrict__ W,
                                                        bf16_t* __restrict__ Bt,
                                                        int KDin, int MDin) {
  __shared__ float tile[64][65];
  const int bm = blockIdx.x, bk = blockIdx.y;
  const int c = threadIdx.x & 63, r0 = threadIdx.x >> 6;
#pragma unroll
  for (int rr = 0; rr < 16; ++rr) {
    int row = rr * 4 + r0;
    tile[row][c] = W[(size_t)(bk * 64 + row) * MDin + bm * 64 + c];
  }
  __syncthreads();
#pragma unroll
  for (int rr = 0; rr < 16; ++rr) {
    int mo = rr * 4 + r0;
    Bt[(size_t)(bm * 64 + mo) * KDin + bk * 64 + c] = (bf16_t)tile[c][mo];
  }
}

// ---------------- feat[order[j]] -> bf16 featp[j]; also emit posf[j][3] --------
__global__ __launch_bounds__(256) void gather_cast_k(const float* __restrict__ feat,
                                                     const int* __restrict__ order,
                                                     const int* __restrict__ grid_coord,
                                                     bf16_t* __restrict__ featp,
                                                     float* __restrict__ posf) {
  const int id = blockIdx.x * 256 + threadIdx.x;  // 32768*192 total
  const int j = id / 192;
  const int c = (id % 192) * 4;
  const int g = order[j];
  const float4 v = *(const float4*)(feat + (size_t)g * 768 + c);
  bf16x4 o;
  o[0] = (bf16_t)v.x; o[1] = (bf16_t)v.y; o[2] = (bf16_t)v.z; o[3] = (bf16_t)v.w;
  *(bf16x4*)(featp + (size_t)j * 768 + c) = o;
  if (c == 0) {
    posf[j * 3 + 0] = (float)grid_coord[g * 3 + 0];
    posf[j * 3 + 1] = (float)grid_coord[g * 3 + 1];
    posf[j * 3 + 2] = (float)grid_coord[g * 3 + 2];
  }
}

// ---------------- 256x256 deep-pipelined GEMM: C[j][m] = A[j][:].Bt[m][:]+bias --
// (unchanged from round 3 — see comments there)
template <int MODE, int NBX>
__global__ __launch_bounds__(512, 2) void gemm256_k(const bf16_t* __restrict__ A,
                                                    const bf16_t* __restrict__ Bt,
                                                    const float* __restrict__ bias,
                                                    bf16_t* __restrict__ Cq,
                                                    bf16_t* __restrict__ Ck,
                                                    bf16_t* __restrict__ Cv,
                                                    float* __restrict__ Cf,
                                                    const int* __restrict__ order,
                                                    const float* __restrict__ posf) {
  extern __shared__ bf16_t sm[];          // [4][8192] A bufs, then [4][8192] B bufs
  bf16_t* ldsA = sm;
  bf16_t* ldsB = sm + 4 * 8192;

  const int tid = threadIdx.x;
  const int lane = tid & 63, wave = tid >> 6;
  const int wr = wave >> 2, wc = wave & 3;  // 2 x 4 wave grid
  const int lq = lane & 15, lk = lane >> 4;

  const int bid = blockIdx.x;
  const int cpx = gridDim.x >> 3;         // gridDim.x % 8 == 0
  const int rm = (bid & 7) * cpx + (bid >> 3);
  const int by = rm / NBX, bx = rm % NBX;

  const int o0 = tid, o1 = tid + 512;
  const int r0s = o0 >> 2, ls0 = (o0 & 3) ^ ((r0s >> 1) & 3);
  const int r1s = o1 >> 2, ls1 = (o1 & 3) ^ ((r1s >> 1) & 3);
  const bf16_t* pA0 = A + (size_t)(by * 256 + r0s) * 768 + ls0 * 8;
  const bf16_t* pA1 = A + (size_t)(by * 256 + r1s) * 768 + ls1 * 8;
  const bf16_t* pB0 = Bt + (size_t)(bx * 256 + r0s) * 768 + ls0 * 8;
  const bf16_t* pB1 = Bt + (size_t)(bx * 256 + r1s) * 768 + ls1 * 8;

  auto stageA = [&](int kt) {
    bf16_t* d = ldsA + ((kt & 3) << 13);
    gload_lds16(pA0 + kt * 32, d + o0 * 8);
    gload_lds16(pA1 + kt * 32, d + o1 * 8);
  };
  auto stageB = [&](int kt) {
    bf16_t* d = ldsB + ((kt & 3) << 13);
    gload_lds16(pB0 + kt * 32, d + o0 * 8);
    gload_lds16(pB1 + kt * 32, d + o1 * 8);
  };

  const int pslot = lk ^ ((lq >> 1) & 3);

  f32x4 acc[8][4] = {};

  stageA(0); stageB(0); stageA(1); stageB(1); stageA(2); stageB(2);
  asm volatile("s_waitcnt vmcnt(8)" ::: "memory");
  __builtin_amdgcn_s_barrier();
  __builtin_amdgcn_sched_barrier(0);

  auto group = [&](int t, auto VMC, auto STGC) {
    constexpr int VM = decltype(VMC)::value;
    constexpr bool STG = decltype(STGC)::value;
    const bf16_t* Ab = ldsA + ((t & 3) << 13);
    const bf16_t* Bb = ldsB + ((t & 3) << 13);
    bf16x8 af[4], bfr[4];
    // ---- phase 1: mh = 0 ----
#pragma unroll
    for (int m = 0; m < 4; ++m)
      af[m] = *(const bf16x8*)(Ab + (wr * 128 + m * 16 + lq) * 32 + pslot * 8);
#pragma unroll
    for (int n = 0; n < 4; ++n)
      bfr[n] = *(const bf16x8*)(Bb + (wc * 64 + n * 16 + lq) * 32 + pslot * 8);
    if constexpr (STG) stageA(t + 3);
    __builtin_amdgcn_s_barrier();
    asm volatile("s_waitcnt lgkmcnt(0)" ::: "memory");
    __builtin_amdgcn_s_setprio(1);
#pragma unroll
    for (int n = 0; n < 4; ++n)
#pragma unroll
      for (int m = 0; m < 4; ++m)
        acc[m][n] = __builtin_amdgcn_mfma_f32_16x16x32_bf16(af[m], bfr[n], acc[m][n], 0, 0, 0);
    __builtin_amdgcn_s_setprio(0);
    __builtin_amdgcn_s_barrier();
    // ---- phase 2: mh = 1 (reuse bfr) ----
#pragma unroll
    for (int m = 0; m < 4; ++m)
      af[m] = *(const bf16x8*)(Ab + (wr * 128 + 64 + m * 16 + lq) * 32 + pslot * 8);
    if constexpr (STG) stageB(t + 3);
    if constexpr (VM == 8) asm volatile("s_waitcnt vmcnt(8)" ::: "memory");
    else if constexpr (VM == 4) asm volatile("s_waitcnt vmcnt(4)" ::: "memory");
    else if constexpr (VM == 0) asm volatile("s_waitcnt vmcnt(0)" ::: "memory");
    __builtin_amdgcn_s_barrier();
    asm volatile("s_waitcnt lgkmcnt(0)" ::: "memory");
    __builtin_amdgcn_s_setprio(1);
#pragma unroll
    for (int n = 0; n < 4; ++n)
#pragma unroll
      for (int m = 0; m < 4; ++m)
        acc[4 + m][n] = __builtin_amdgcn_mfma_f32_16x16x32_bf16(af[m], bfr[n], acc[4 + m][n], 0, 0, 0);
    __builtin_amdgcn_s_setprio(0);
    __builtin_amdgcn_s_barrier();
    __builtin_amdgcn_sched_barrier(0);
  };

  for (int t = 0; t < 21; ++t) group(t, ic<8>{}, ic<1>{});
  group(21, ic<4>{}, ic<0>{});
  group(22, ic<0>{}, ic<0>{});
  group(23, ic<-1>{}, ic<0>{});

  // ---- epilogue ----
  const int colb = bx * 256 + wc * 64;
  float bcol[4];
#pragma unroll
  for (int n = 0; n < 4; ++n) bcol[n] = bias[colb + n * 16 + lq];

  if (MODE == 0) {
    const int sec = bx / 3;               // 0=Q, 1=K, 2=V  (NBX==9, 768%256==0)
    const int coll = colb - sec * 768;
    if (sec < 2) {
      bf16_t* base = sec == 0 ? Cq : Ck;
      const int a0 = (colb % 96) >> 5;
      const int a1 = ((colb + 32) % 96) >> 5;
      const float fr = exp2f(-0.41524101186f * (float)lq);  // 100^(-lq/16)
#pragma unroll
      for (int m = 0; m < 8; ++m) {
        const int rowb = by * 256 + wr * 128 + m * 16 + lk * 4;
#pragma unroll
        for (int r = 0; r < 4; ++r) {
          const int row = rowb + r;
          float s0, c0, s1, c1;
          __sincosf(posf[row * 3 + a0] * fr, &s0, &c0);
          __sincosf(posf[row * 3 + a1] * fr, &s1, &c1);
          const float x1 = acc[m][0][r] + bcol[0], x2 = acc[m][1][r] + bcol[1];
          const float y1 = acc[m][2][r] + bcol[2], y2 = acc[m][3][r] + bcol[3];
          acc[m][0][r] = x1 * c0 - x2 * s0;
          acc[m][1][r] = x1 * s0 + x2 * c0;
          acc[m][2][r] = y1 * c1 - y2 * s1;
          acc[m][3][r] = y1 * s1 + y2 * c1;
        }
#pragma unroll
        for (int n = 0; n < 4; ++n) {
          const int col = coll + n * 16 + lq;
#pragma unroll
          for (int r = 0; r < 4; ++r)
            base[(size_t)(rowb + r) * 768 + col] = (bf16_t)acc[m][n][r];
        }
      }
    } else {
      // V: store TRANSPOSED -> Cv = Vt[feat][token].
#pragma unroll
      for (int m = 0; m < 8; ++m) {
        const int rowb = by * 256 + wr * 128 + m * 16 + lk * 4;
#pragma unroll
        for (int n = 0; n < 4; ++n) {
          const int col = coll + n * 16 + lq;
          bf16x4 o;
#pragma unroll
          for (int r = 0; r < 4; ++r) o[r] = (bf16_t)(acc[m][n][r] + bcol[n]);
          *(bf16x4*)(Cv + (size_t)col * 32768 + rowb) = o;
        }
      }
    }
  } else {
#pragma unroll
    for (int m = 0; m < 8; ++m) {
      const int rowb = by * 256 + wr * 128 + m * 16 + lk * 4;
      int ro[4];
#pragma unroll
      for (int r = 0; r < 4; ++r) ro[r] = order[rowb + r];
#pragma unroll
      for (int n = 0; n < 4; ++n) {
        const int col = colb + n * 16 + lq;
#pragma unroll
        for (int r = 0; r < 4; ++r)
          Cf[(size_t)ro[r] * 768 + col] = acc[m][n][r] + bcol[n];
      }
    }
  }
}

// ---------------- windowed attention v5: one block per (p,h), 8 waves ----------
// 1024 blocks x 512 thr.  Dynamic LDS 128KB: K frags 48KB + V frags 48KB
// (both staged ONCE, co-resident) + 8 per-wave 4KB swizzled P buffers.
// Each wave owns 32 q-rows = 2 sequential 16-row sub-blocks (rb), keeping
// sacc at 16 f32x4.  Stage order: Q->regs, K, V (all async; sched_barrier
// pins Q-before-K issue so the vmcnt(6) accounting holds).  vmcnt(6)+barrier
// releases QK (Q + K done, V still in flight); QK(rb0)+softmax(rb0) overlap
// V's arrival; vmcnt(0)+barrier before first PV (also guarantees every wave's
// Q loads completed -> O-over-Q write is safe).  K stays resident, so rb1
// needs no further barriers.
__global__ __launch_bounds__(512) void attn_k(bf16_t* QO,   // Q in, O out (same buffer)
                                              const bf16_t* __restrict__ Kb,
                                              const bf16_t* __restrict__ Vt) {
  extern __shared__ bf16_t alds[];
  bf16_t* Kreg = alds;            // 24576 bf16 (48KB)
  bf16_t* Vreg = alds + 24576;    // 24576 bf16 (48KB)
  const int bid = blockIdx.x;
  const int h = bid & 7, p = bid >> 3;
  const int tid = threadIdx.x, lane = tid & 63, wave = tid >> 6;
  const int lq = lane & 15, lk = lane >> 4;
  const int tok0 = p * 256;
  const float scale = 0.10206207262f;  // 96^-0.5
  bf16_t* pw = alds + 49152 + wave * 2048;  // per-wave 16x128 swizzled P half

  // ---- Q -> regs first (so vmcnt(6) below covers them) ----
  bf16x8 aq[2][3];
#pragma unroll
  for (int rb = 0; rb < 2; ++rb) {
    const bf16_t* qb = QO + (size_t)(tok0 + wave * 32 + rb * 16 + lq) * 768 + h * 96 + lk * 8;
#pragma unroll
    for (int kc = 0; kc < 3; ++kc) aq[rb][kc] = *(const bf16x8*)(qb + kc * 32);
  }
  __builtin_amdgcn_sched_barrier(0);   // pin Q-load issue before K/V staging

  // ---- stage K frags (6 x 512 chunks), straight from row-major Kb.
  // chunk c = i*512 + tid; fi = c>>6 = i*8 + wave; frag (fi,lane) =
  // Kb[tok0 + (fi/3)*16 + (lane&15)][h*96 + (fi%3)*32 + (lane>>4)*8 ..+7]
#pragma unroll
  for (int i = 0; i < 6; ++i) {
    const int fi = i * 8 + wave;
    const int nt = fi / 3, a = fi - nt * 3;
    const bf16_t* src = Kb + (size_t)(tok0 + nt * 16 + (lane & 15)) * 768 +
                        h * 96 + a * 32 + (lane >> 4) * 8;
    gload_lds16(src, Kreg + i * 4096 + tid * 8);
  }
  // ---- stage V frags from transposed Vt[feat][token]:
  // frag (fi,lane): d = (fi>>3)*16 + (lane&15), tb = (fi&7)*32 + (lane>>4)*8
#pragma unroll
  for (int i = 0; i < 6; ++i) {
    const int fi = i * 8 + wave;
    const int d = (fi >> 3) * 16 + (lane & 15);
    const int tb = (fi & 7) * 32 + (lane >> 4) * 8;
    const bf16_t* src = Vt + (size_t)(h * 96 + d) * 32768 + tok0 + tb;
    gload_lds16(src, Vreg + i * 4096 + tid * 8);
  }

  asm volatile("s_waitcnt vmcnt(6)" ::: "memory");   // Q + K complete
  __builtin_amdgcn_s_barrier();

#pragma unroll
  for (int rb = 0; rb < 2; ++rb) {
    // ---- S = Q.K^T from LDS
    f32x4 sacc[16];
#pragma unroll
    for (int nt = 0; nt < 16; ++nt) {
      f32x4 acc = {0.f, 0.f, 0.f, 0.f};
#pragma unroll
      for (int kc = 0; kc < 3; ++kc) {
        bf16x8 bk = *(const bf16x8*)(Kreg + (size_t)((nt * 3 + kc) * 64 + lane) * 8);
        acc = __builtin_amdgcn_mfma_f32_16x16x32_bf16(aq[rb][kc], bk, acc, 0, 0, 0);
      }
      sacc[nt] = acc;
    }

    // ---- softmax (rows in C-layout: row = lk*4+r, col = nt*16+lq)
    float linv[4];
#pragma unroll
    for (int r = 0; r < 4; ++r) {
      float mx = -1e30f;
#pragma unroll
      for (int nt = 0; nt < 16; ++nt) mx = fmaxf(mx, sacc[nt][r]);
      mx = fmaxf(mx, __shfl_xor(mx, 1));
      mx = fmaxf(mx, __shfl_xor(mx, 2));
      mx = fmaxf(mx, __shfl_xor(mx, 4));
      mx = fmaxf(mx, __shfl_xor(mx, 8));
      mx *= scale;
      float l = 0.f;
#pragma unroll
      for (int nt = 0; nt < 16; ++nt) {
        float e = __expf(sacc[nt][r] * scale - mx);
        sacc[nt][r] = e;
        l += e;
      }
      l += __shfl_xor(l, 1);
      l += __shfl_xor(l, 2);
      l += __shfl_xor(l, 4);
      l += __shfl_xor(l, 8);
      linv[r] = 1.f / l;
    }

    if (rb == 0) {
      asm volatile("s_waitcnt vmcnt(0)" ::: "memory");  // V staged (all waves)
      __builtin_amdgcn_s_barrier();
    }

    // ---- PV in two 128-token halves through private swizzled P buffer.
    // Same-wave DS ops are in-order, so no barrier needed around pw.
    f32x4 oacc[6] = {};
#pragma unroll
    for (int hf = 0; hf < 2; ++hf) {
#pragma unroll
      for (int ntl = 0; ntl < 8; ++ntl) {
        const int nt = hf * 8 + ntl;
        const int chk = ntl * 2 + (lq >> 3);
#pragma unroll
        for (int r = 0; r < 4; ++r) {
          const int row = lk * 4 + r;
          const int phys = chk ^ (row & 7);
          pw[row * 128 + phys * 8 + (lq & 7)] = (bf16_t)sacc[nt][r];
        }
      }
#pragma unroll
      for (int kcl = 0; kcl < 4; ++kcl) {
        const int physr = (kcl * 4 + lk) ^ (lq & 7);
        bf16x8 pf = *(const bf16x8*)(pw + lq * 128 + physr * 8);
        const int kc = hf * 4 + kcl;
#pragma unroll
        for (int dt = 0; dt < 6; ++dt) {
          bf16x8 vb = *(const bf16x8*)(Vreg + (size_t)((dt * 8 + kc) * 64 + lane) * 8);
          oacc[dt] = __builtin_amdgcn_mfma_f32_16x16x32_bf16(pf, vb, oacc[dt], 0, 0, 0);
        }
      }
    }

    // ---- write O over Q (all global Q loads completed at the rb0 barrier)
#pragma unroll
    for (int dt = 0; dt < 6; ++dt) {
#pragma unroll
      for (int r = 0; r < 4; ++r) {
        const int row = tok0 + wave * 32 + rb * 16 + lk * 4 + r;
        QO[(size_t)row * 768 + h * 96 + dt * 16 + lq] = (bf16_t)(oacc[dt][r] * linv[r]);
      }
    }
  }
}

extern "C" void kernel_launch(void* const* d_in, const int* in_sizes, int n_in,
                              void* d_out, int out_size, void* d_ws, size_t ws_size,
                              hipStream_t stream) {
  const float* feat       = (const float*)d_in[0];
  const int*   grid_coord = (const int*)d_in[1];
  const int*   order      = (const int*)d_in[2];
  // d_in[3] = inverse (unused: scatter-by-order is equivalent)
  const float* w_qkv      = (const float*)d_in[4];
  const float* b_qkv      = (const float*)d_in[5];
  const float* w_proj     = (const float*)d_in[6];
  const float* b_proj     = (const float*)d_in[7];
  float* out = (float*)d_out;

  char* ws = (char*)d_ws;
  bf16_t* Bt1   = (bf16_t*)(ws);                 // 2304x768  bf16
  bf16_t* Bt2   = (bf16_t*)(ws + 3538944);       // 768x768   bf16
  bf16_t* featp = (bf16_t*)(ws + 4718592);       // 32768x768 bf16
  bf16_t* Qb    = (bf16_t*)(ws + 55050240);      // 32768x768 bf16
  bf16_t* Kb    = (bf16_t*)(ws + 105381888);     // 32768x768 bf16
  bf16_t* Vt    = (bf16_t*)(ws + 155713536);     // 768x32768 bf16 (V transposed)
  float*  posf  = (float*)(ws + 206045184);      // 32768x3 fp32

  static bool attr_set = false;
  if (!attr_set) {
    (void)hipFuncSetAttribute((const void*)gemm256_k<0, 9>,
                              hipFuncAttributeMaxDynamicSharedMemorySize, 131072);
    (void)hipFuncSetAttribute((const void*)gemm256_k<1, 3>,
                              hipFuncAttributeMaxDynamicSharedMemorySize, 131072);
    (void)hipFuncSetAttribute((const void*)attn_k,
                              hipFuncAttributeMaxDynamicSharedMemorySize, 131072);
    attr_set = true;
  }

  transpose_cast_k<<<dim3(36, 12), 256, 0, stream>>>(w_qkv, Bt1, 768, 2304);
  transpose_cast_k<<<dim3(12, 12), 256, 0, stream>>>(w_proj, Bt2, 768, 768);
  gather_cast_k<<<24576, 256, 0, stream>>>(feat, order, grid_coord, featp, posf);
  gemm256_k<0, 9><<<1152, 512, 131072, stream>>>(featp, Bt1, b_qkv, Qb, Kb, Vt,
                                                 nullptr, nullptr, posf);
  attn_k<<<1024, 512, 131072, stream>>>(Qb, Kb, Vt);
  gemm256_k<1, 3><<<384, 512, 131072, stream>>>(Qb, Bt2, b_proj, nullptr, nullptr,
                                                nullptr, out, order, nullptr);
}

// Round 6
// 478.642 us; speedup vs baseline: 1.0119x; 1.0119x over previous
//
#include <hip/hip_runtime.h>
#include <hip/hip_bf16.h>
#include <stdint.h>

typedef __bf16 bf16_t;
typedef __bf16 bf16x8 __attribute__((ext_vector_type(8)));
typedef __bf16 bf16x4 __attribute__((ext_vector_type(4)));
typedef float f32x4 __attribute__((ext_vector_type(4)));

template <int V> struct ic { static constexpr int value = V; };

// async global->LDS, 16B per lane. LDS dest must be wave-uniform base + lane*16;
// the GLOBAL source is per-lane (used to fold gathers/permutations into staging).
__device__ __forceinline__ void gload_lds16(const bf16_t* g, bf16_t* l) {
  __builtin_amdgcn_global_load_lds((const __attribute__((address_space(1))) void*)g,
                                   (__attribute__((address_space(3))) void*)l, 16, 0, 0);
}

// ---------------- fp32 W[k][m] -> bf16 Bt[m][k] (tiled transpose + cast) --------
__global__ __launch_bounds__(256) void transpose_cast_k(const float* __restrict__ W,
                                                        bf16_t* __restrict__ Bt,
                                                        int KDin, int MDin) {
  __shared__ float tile[64][65];
  const int bm = blockIdx.x, bk = blockIdx.y;
  const int c = threadIdx.x & 63, r0 = threadIdx.x >> 6;
#pragma unroll
  for (int rr = 0; rr < 16; ++rr) {
    int row = rr * 4 + r0;
    tile[row][c] = W[(size_t)(bk * 64 + row) * MDin + bm * 64 + c];
  }
  __syncthreads();
#pragma unroll
  for (int rr = 0; rr < 16; ++rr) {
    int mo = rr * 4 + r0;
    Bt[(size_t)(bm * 64 + mo) * KDin + bk * 64 + c] = (bf16_t)tile[c][mo];
  }
}

// ---------------- feat[order[j]] -> bf16 featp[j]; also emit posf[j][3] --------
__global__ __launch_bounds__(256) void gather_cast_k(const float* __restrict__ feat,
                                                     const int* __restrict__ order,
                                                     const int* __restrict__ grid_coord,
                                                     bf16_t* __restrict__ featp,
                                                     float* __restrict__ posf) {
  const int id = blockIdx.x * 256 + threadIdx.x;  // 32768*192 total
  const int j = id / 192;
  const int c = (id % 192) * 4;
  const int g = order[j];
  const float4 v = *(const float4*)(feat + (size_t)g * 768 + c);
  bf16x4 o;
  o[0] = (bf16_t)v.x; o[1] = (bf16_t)v.y; o[2] = (bf16_t)v.z; o[3] = (bf16_t)v.w;
  *(bf16x4*)(featp + (size_t)j * 768 + c) = o;
  if (c == 0) {
    posf[j * 3 + 0] = (float)grid_coord[g * 3 + 0];
    posf[j * 3 + 1] = (float)grid_coord[g * 3 + 1];
    posf[j * 3 + 2] = (float)grid_coord[g * 3 + 2];
  }
}

// ---------------- 256x256 deep-pipelined GEMM (QKV): unchanged from r3 ----------
template <int MODE, int NBX>
__global__ __launch_bounds__(512, 2) void gemm256_k(const bf16_t* __restrict__ A,
                                                    const bf16_t* __restrict__ Bt,
                                                    const float* __restrict__ bias,
                                                    bf16_t* __restrict__ Cq,
                                                    bf16_t* __restrict__ Ck,
                                                    bf16_t* __restrict__ Cv,
                                                    float* __restrict__ Cf,
                                                    const int* __restrict__ order,
                                                    const float* __restrict__ posf) {
  extern __shared__ bf16_t sm[];          // [4][8192] A bufs, then [4][8192] B bufs
  bf16_t* ldsA = sm;
  bf16_t* ldsB = sm + 4 * 8192;

  const int tid = threadIdx.x;
  const int lane = tid & 63, wave = tid >> 6;
  const int wr = wave >> 2, wc = wave & 3;  // 2 x 4 wave grid
  const int lq = lane & 15, lk = lane >> 4;

  const int bid = blockIdx.x;
  const int cpx = gridDim.x >> 3;         // gridDim.x % 8 == 0
  const int rm = (bid & 7) * cpx + (bid >> 3);
  const int by = rm / NBX, bx = rm % NBX;

  const int o0 = tid, o1 = tid + 512;
  const int r0s = o0 >> 2, ls0 = (o0 & 3) ^ ((r0s >> 1) & 3);
  const int r1s = o1 >> 2, ls1 = (o1 & 3) ^ ((r1s >> 1) & 3);
  const bf16_t* pA0 = A + (size_t)(by * 256 + r0s) * 768 + ls0 * 8;
  const bf16_t* pA1 = A + (size_t)(by * 256 + r1s) * 768 + ls1 * 8;
  const bf16_t* pB0 = Bt + (size_t)(bx * 256 + r0s) * 768 + ls0 * 8;
  const bf16_t* pB1 = Bt + (size_t)(bx * 256 + r1s) * 768 + ls1 * 8;

  auto stageA = [&](int kt) {
    bf16_t* d = ldsA + ((kt & 3) << 13);
    gload_lds16(pA0 + kt * 32, d + o0 * 8);
    gload_lds16(pA1 + kt * 32, d + o1 * 8);
  };
  auto stageB = [&](int kt) {
    bf16_t* d = ldsB + ((kt & 3) << 13);
    gload_lds16(pB0 + kt * 32, d + o0 * 8);
    gload_lds16(pB1 + kt * 32, d + o1 * 8);
  };

  const int pslot = lk ^ ((lq >> 1) & 3);

  f32x4 acc[8][4] = {};

  stageA(0); stageB(0); stageA(1); stageB(1); stageA(2); stageB(2);
  asm volatile("s_waitcnt vmcnt(8)" ::: "memory");
  __builtin_amdgcn_s_barrier();
  __builtin_amdgcn_sched_barrier(0);

  auto group = [&](int t, auto VMC, auto STGC) {
    constexpr int VM = decltype(VMC)::value;
    constexpr bool STG = decltype(STGC)::value;
    const bf16_t* Ab = ldsA + ((t & 3) << 13);
    const bf16_t* Bb = ldsB + ((t & 3) << 13);
    bf16x8 af[4], bfr[4];
    // ---- phase 1: mh = 0 ----
#pragma unroll
    for (int m = 0; m < 4; ++m)
      af[m] = *(const bf16x8*)(Ab + (wr * 128 + m * 16 + lq) * 32 + pslot * 8);
#pragma unroll
    for (int n = 0; n < 4; ++n)
      bfr[n] = *(const bf16x8*)(Bb + (wc * 64 + n * 16 + lq) * 32 + pslot * 8);
    if constexpr (STG) stageA(t + 3);
    __builtin_amdgcn_s_barrier();
    asm volatile("s_waitcnt lgkmcnt(0)" ::: "memory");
    __builtin_amdgcn_s_setprio(1);
#pragma unroll
    for (int n = 0; n < 4; ++n)
#pragma unroll
      for (int m = 0; m < 4; ++m)
        acc[m][n] = __builtin_amdgcn_mfma_f32_16x16x32_bf16(af[m], bfr[n], acc[m][n], 0, 0, 0);
    __builtin_amdgcn_s_setprio(0);
    __builtin_amdgcn_s_barrier();
    // ---- phase 2: mh = 1 (reuse bfr) ----
#pragma unroll
    for (int m = 0; m < 4; ++m)
      af[m] = *(const bf16x8*)(Ab + (wr * 128 + 64 + m * 16 + lq) * 32 + pslot * 8);
    if constexpr (STG) stageB(t + 3);
    if constexpr (VM == 8) asm volatile("s_waitcnt vmcnt(8)" ::: "memory");
    else if constexpr (VM == 4) asm volatile("s_waitcnt vmcnt(4)" ::: "memory");
    else if constexpr (VM == 0) asm volatile("s_waitcnt vmcnt(0)" ::: "memory");
    __builtin_amdgcn_s_barrier();
    asm volatile("s_waitcnt lgkmcnt(0)" ::: "memory");
    __builtin_amdgcn_s_setprio(1);
#pragma unroll
    for (int n = 0; n < 4; ++n)
#pragma unroll
      for (int m = 0; m < 4; ++m)
        acc[4 + m][n] = __builtin_amdgcn_mfma_f32_16x16x32_bf16(af[m], bfr[n], acc[4 + m][n], 0, 0, 0);
    __builtin_amdgcn_s_setprio(0);
    __builtin_amdgcn_s_barrier();
    __builtin_amdgcn_sched_barrier(0);
  };

  for (int t = 0; t < 21; ++t) group(t, ic<8>{}, ic<1>{});
  group(21, ic<4>{}, ic<0>{});
  group(22, ic<0>{}, ic<0>{});
  group(23, ic<-1>{}, ic<0>{});

  // ---- epilogue ----
  const int colb = bx * 256 + wc * 64;
  float bcol[4];
#pragma unroll
  for (int n = 0; n < 4; ++n) bcol[n] = bias[colb + n * 16 + lq];

  if (MODE == 0) {
    const int sec = bx / 3;               // 0=Q, 1=K, 2=V  (NBX==9, 768%256==0)
    const int coll = colb - sec * 768;
    if (sec < 2) {
      bf16_t* base = sec == 0 ? Cq : Ck;
      const int a0 = (colb % 96) >> 5;
      const int a1 = ((colb + 32) % 96) >> 5;
      const float fr = exp2f(-0.41524101186f * (float)lq);  // 100^(-lq/16)
#pragma unroll
      for (int m = 0; m < 8; ++m) {
        const int rowb = by * 256 + wr * 128 + m * 16 + lk * 4;
#pragma unroll
        for (int r = 0; r < 4; ++r) {
          const int row = rowb + r;
          float s0, c0, s1, c1;
          __sincosf(posf[row * 3 + a0] * fr, &s0, &c0);
          __sincosf(posf[row * 3 + a1] * fr, &s1, &c1);
          const float x1 = acc[m][0][r] + bcol[0], x2 = acc[m][1][r] + bcol[1];
          const float y1 = acc[m][2][r] + bcol[2], y2 = acc[m][3][r] + bcol[3];
          acc[m][0][r] = x1 * c0 - x2 * s0;
          acc[m][1][r] = x1 * s0 + x2 * c0;
          acc[m][2][r] = y1 * c1 - y2 * s1;
          acc[m][3][r] = y1 * s1 + y2 * c1;
        }
#pragma unroll
        for (int n = 0; n < 4; ++n) {
          const int col = coll + n * 16 + lq;
#pragma unroll
          for (int r = 0; r < 4; ++r)
            base[(size_t)(rowb + r) * 768 + col] = (bf16_t)acc[m][n][r];
        }
      }
    } else {
      // V: store TRANSPOSED -> Cv = Vt[feat][token].
#pragma unroll
      for (int m = 0; m < 8; ++m) {
        const int rowb = by * 256 + wr * 128 + m * 16 + lk * 4;
#pragma unroll
        for (int n = 0; n < 4; ++n) {
          const int col = coll + n * 16 + lq;
          bf16x4 o;
#pragma unroll
          for (int r = 0; r < 4; ++r) o[r] = (bf16_t)(acc[m][n][r] + bcol[n]);
          *(bf16x4*)(Cv + (size_t)col * 32768 + rowb) = o;
        }
      }
    }
  } else {
#pragma unroll
    for (int m = 0; m < 8; ++m) {
      const int rowb = by * 256 + wr * 128 + m * 16 + lk * 4;
      int ro[4];
#pragma unroll
      for (int r = 0; r < 4; ++r) ro[r] = order[rowb + r];
#pragma unroll
      for (int n = 0; n < 4; ++n) {
        const int col = colb + n * 16 + lq;
#pragma unroll
        for (int r = 0; r < 4; ++r)
          Cf[(size_t)ro[r] * 768 + col] = acc[m][n][r] + bcol[n];
      }
    }
  }
}

// ---------------- projection GEMM (out-of-order-free): out[i] = Qb[inv[i]].Bt2 --
// BM=128 x BN=256, grid = 256 by-tiles * 3 bx = 768 blocks = EXACTLY 3 full-chip
// rounds (no tail).  A-rows gathered through inverse[] in the per-lane GLOBAL
// source of global_load_lds (Qb is L3-resident after attn); C-writes are dense
// coalesced fp32 streams (replaces the random-row scatter).  LDS = ring of 4
// K-tile buffers (A 8KB + B 16KB) = 96KB.  One phase per BK=32 K-tile:
// { 8 ds_read | stage(t+3): 3 loads | vmcnt(6) | barrier | lgkm0+sched_barrier
//   | 16 MFMA (setprio) | barrier }.  Drain vmcnt 3->0 at the end.
// Same XOR slot swizzle as gemm256 (pre-swizzled source + swizzled ds_read).
__global__ __launch_bounds__(512, 2) void gemm_proj_k(const bf16_t* __restrict__ A,
                                                      const bf16_t* __restrict__ Bt,
                                                      const float* __restrict__ bias,
                                                      float* __restrict__ Cf,
                                                      const int* __restrict__ inverse) {
  extern __shared__ bf16_t sm[];
  bf16_t* ldsA = sm;            // 4 slots x 4096 bf16 (8KB)  = 32KB
  bf16_t* ldsB = sm + 16384;    // 4 slots x 8192 bf16 (16KB) = 64KB

  const int tid = threadIdx.x;
  const int lane = tid & 63, wave = tid >> 6;
  const int wr = wave >> 2, wc = wave & 3;  // 2 x 4 wave grid
  const int lq = lane & 15, lk = lane >> 4;

  const int bid = blockIdx.x;
  const int cpx = gridDim.x >> 3;           // 768/8 = 96
  const int rm = (bid & 7) * cpx + (bid >> 3);
  const int by = rm / 3, bx = rm % 3;

  // A: 512 16B-units (128 rows x 4 slots), 1 unit/thread, row gathered via inverse.
  const int rA = tid >> 2, lsA = (tid & 3) ^ ((rA >> 1) & 3);
  const int gA = inverse[by * 128 + rA];
  const bf16_t* pA = A + (size_t)gA * 768 + lsA * 8;
  // B: 1024 units (256 rows x 4 slots), 2 units/thread.
  const int o0 = tid, o1 = tid + 512;
  const int rB0 = o0 >> 2, lsB0 = (o0 & 3) ^ ((rB0 >> 1) & 3);
  const int rB1 = o1 >> 2, lsB1 = (o1 & 3) ^ ((rB1 >> 1) & 3);
  const bf16_t* pB0 = Bt + (size_t)(bx * 256 + rB0) * 768 + lsB0 * 8;
  const bf16_t* pB1 = Bt + (size_t)(bx * 256 + rB1) * 768 + lsB1 * 8;

  auto stage = [&](int kt) {
    const int slot = kt & 3;
    gload_lds16(pA + kt * 32, ldsA + (slot << 12) + tid * 8);
    gload_lds16(pB0 + kt * 32, ldsB + (slot << 13) + o0 * 8);
    gload_lds16(pB1 + kt * 32, ldsB + (slot << 13) + o1 * 8);
  };

  const int pslot = lk ^ ((lq >> 1) & 3);

  f32x4 acc[4][4] = {};

  // prologue: 3 tiles in flight (9 loads); oldest 3 (= tile 0) must land.
  stage(0); stage(1); stage(2);
  asm volatile("s_waitcnt vmcnt(6)" ::: "memory");
  __builtin_amdgcn_s_barrier();
  __builtin_amdgcn_sched_barrier(0);

  auto group = [&](int t, auto VMC, auto STGC) {
    constexpr int VM = decltype(VMC)::value;
    constexpr bool STG = decltype(STGC)::value;
    const bf16_t* Ab = ldsA + ((t & 3) << 12);
    const bf16_t* Bb = ldsB + ((t & 3) << 13);
    bf16x8 af[4], bfr[4];
#pragma unroll
    for (int m = 0; m < 4; ++m)
      af[m] = *(const bf16x8*)(Ab + (wr * 64 + m * 16 + lq) * 32 + pslot * 8);
#pragma unroll
    for (int n = 0; n < 4; ++n)
      bfr[n] = *(const bf16x8*)(Bb + (wc * 64 + n * 16 + lq) * 32 + pslot * 8);
    if constexpr (STG) stage(t + 3);
    if constexpr (VM == 6) asm volatile("s_waitcnt vmcnt(6)" ::: "memory");
    else if constexpr (VM == 3) asm volatile("s_waitcnt vmcnt(3)" ::: "memory");
    else if constexpr (VM == 0) asm volatile("s_waitcnt vmcnt(0)" ::: "memory");
    __builtin_amdgcn_s_barrier();
    asm volatile("s_waitcnt lgkmcnt(0)" ::: "memory");
    __builtin_amdgcn_sched_barrier(0);
    __builtin_amdgcn_s_setprio(1);
#pragma unroll
    for (int n = 0; n < 4; ++n)
#pragma unroll
      for (int m = 0; m < 4; ++m)
        acc[m][n] = __builtin_amdgcn_mfma_f32_16x16x32_bf16(af[m], bfr[n], acc[m][n], 0, 0, 0);
    __builtin_amdgcn_s_setprio(0);
    __builtin_amdgcn_s_barrier();
    __builtin_amdgcn_sched_barrier(0);
  };

  for (int t = 0; t < 21; ++t) group(t, ic<6>{}, ic<1>{});
  group(21, ic<3>{}, ic<0>{});
  group(22, ic<0>{}, ic<0>{});
  group(23, ic<-1>{}, ic<0>{});

  // ---- epilogue: dense coalesced fp32 rows in ORIGINAL order ----
  const int colb = bx * 256 + wc * 64;
  float bcol[4];
#pragma unroll
  for (int n = 0; n < 4; ++n) bcol[n] = bias[colb + n * 16 + lq];
#pragma unroll
  for (int m = 0; m < 4; ++m) {
    const int rowb = by * 128 + wr * 64 + m * 16 + lk * 4;
#pragma unroll
    for (int n = 0; n < 4; ++n) {
      const int col = colb + n * 16 + lq;
#pragma unroll
      for (int r = 0; r < 4; ++r)
        Cf[(size_t)(rowb + r) * 768 + col] = acc[m][n][r] + bcol[n];
    }
  }
}

// ---------------- windowed attention v5: one block per (p,h), 8 waves ----------
// (unchanged from round 5 — see comments there)
__global__ __launch_bounds__(512) void attn_k(bf16_t* QO,   // Q in, O out (same buffer)
                                              const bf16_t* __restrict__ Kb,
                                              const bf16_t* __restrict__ Vt) {
  extern __shared__ bf16_t alds[];
  bf16_t* Kreg = alds;            // 24576 bf16 (48KB)
  bf16_t* Vreg = alds + 24576;    // 24576 bf16 (48KB)
  const int bid = blockIdx.x;
  const int h = bid & 7, p = bid >> 3;
  const int tid = threadIdx.x, lane = tid & 63, wave = tid >> 6;
  const int lq = lane & 15, lk = lane >> 4;
  const int tok0 = p * 256;
  const float scale = 0.10206207262f;  // 96^-0.5
  bf16_t* pw = alds + 49152 + wave * 2048;  // per-wave 16x128 swizzled P half

  // ---- Q -> regs first (so vmcnt(6) below covers them) ----
  bf16x8 aq[2][3];
#pragma unroll
  for (int rb = 0; rb < 2; ++rb) {
    const bf16_t* qb = QO + (size_t)(tok0 + wave * 32 + rb * 16 + lq) * 768 + h * 96 + lk * 8;
#pragma unroll
    for (int kc = 0; kc < 3; ++kc) aq[rb][kc] = *(const bf16x8*)(qb + kc * 32);
  }
  __builtin_amdgcn_sched_barrier(0);   // pin Q-load issue before K/V staging

  // ---- stage K frags (6 x 512 chunks), straight from row-major Kb.
#pragma unroll
  for (int i = 0; i < 6; ++i) {
    const int fi = i * 8 + wave;
    const int nt = fi / 3, a = fi - nt * 3;
    const bf16_t* src = Kb + (size_t)(tok0 + nt * 16 + (lane & 15)) * 768 +
                        h * 96 + a * 32 + (lane >> 4) * 8;
    gload_lds16(src, Kreg + i * 4096 + tid * 8);
  }
  // ---- stage V frags from transposed Vt[feat][token].
#pragma unroll
  for (int i = 0; i < 6; ++i) {
    const int fi = i * 8 + wave;
    const int d = (fi >> 3) * 16 + (lane & 15);
    const int tb = (fi & 7) * 32 + (lane >> 4) * 8;
    const bf16_t* src = Vt + (size_t)(h * 96 + d) * 32768 + tok0 + tb;
    gload_lds16(src, Vreg + i * 4096 + tid * 8);
  }

  asm volatile("s_waitcnt vmcnt(6)" ::: "memory");   // Q + K complete
  __builtin_amdgcn_s_barrier();

#pragma unroll
  for (int rb = 0; rb < 2; ++rb) {
    // ---- S = Q.K^T from LDS
    f32x4 sacc[16];
#pragma unroll
    for (int nt = 0; nt < 16; ++nt) {
      f32x4 acc = {0.f, 0.f, 0.f, 0.f};
#pragma unroll
      for (int kc = 0; kc < 3; ++kc) {
        bf16x8 bk = *(const bf16x8*)(Kreg + (size_t)((nt * 3 + kc) * 64 + lane) * 8);
        acc = __builtin_amdgcn_mfma_f32_16x16x32_bf16(aq[rb][kc], bk, acc, 0, 0, 0);
      }
      sacc[nt] = acc;
    }

    // ---- softmax (rows in C-layout: row = lk*4+r, col = nt*16+lq)
    float linv[4];
#pragma unroll
    for (int r = 0; r < 4; ++r) {
      float mx = -1e30f;
#pragma unroll
      for (int nt = 0; nt < 16; ++nt) mx = fmaxf(mx, sacc[nt][r]);
      mx = fmaxf(mx, __shfl_xor(mx, 1));
      mx = fmaxf(mx, __shfl_xor(mx, 2));
      mx = fmaxf(mx, __shfl_xor(mx, 4));
      mx = fmaxf(mx, __shfl_xor(mx, 8));
      mx *= scale;
      float l = 0.f;
#pragma unroll
      for (int nt = 0; nt < 16; ++nt) {
        float e = __expf(sacc[nt][r] * scale - mx);
        sacc[nt][r] = e;
        l += e;
      }
      l += __shfl_xor(l, 1);
      l += __shfl_xor(l, 2);
      l += __shfl_xor(l, 4);
      l += __shfl_xor(l, 8);
      linv[r] = 1.f / l;
    }

    if (rb == 0) {
      asm volatile("s_waitcnt vmcnt(0)" ::: "memory");  // V staged (all waves)
      __builtin_amdgcn_s_barrier();
    }

    // ---- PV in two 128-token halves through private swizzled P buffer.
    f32x4 oacc[6] = {};
#pragma unroll
    for (int hf = 0; hf < 2; ++hf) {
#pragma unroll
      for (int ntl = 0; ntl < 8; ++ntl) {
        const int nt = hf * 8 + ntl;
        const int chk = ntl * 2 + (lq >> 3);
#pragma unroll
        for (int r = 0; r < 4; ++r) {
          const int row = lk * 4 + r;
          const int phys = chk ^ (row & 7);
          pw[row * 128 + phys * 8 + (lq & 7)] = (bf16_t)sacc[nt][r];
        }
      }
#pragma unroll
      for (int kcl = 0; kcl < 4; ++kcl) {
        const int physr = (kcl * 4 + lk) ^ (lq & 7);
        bf16x8 pf = *(const bf16x8*)(pw + lq * 128 + physr * 8);
        const int kc = hf * 4 + kcl;
#pragma unroll
        for (int dt = 0; dt < 6; ++dt) {
          bf16x8 vb = *(const bf16x8*)(Vreg + (size_t)((dt * 8 + kc) * 64 + lane) * 8);
          oacc[dt] = __builtin_amdgcn_mfma_f32_16x16x32_bf16(pf, vb, oacc[dt], 0, 0, 0);
        }
      }
    }

    // ---- write O over Q (all global Q loads completed at the rb0 barrier)
#pragma unroll
    for (int dt = 0; dt < 6; ++dt) {
#pragma unroll
      for (int r = 0; r < 4; ++r) {
        const int row = tok0 + wave * 32 + rb * 16 + lk * 4 + r;
        QO[(size_t)row * 768 + h * 96 + dt * 16 + lq] = (bf16_t)(oacc[dt][r] * linv[r]);
      }
    }
  }
}

extern "C" void kernel_launch(void* const* d_in, const int* in_sizes, int n_in,
                              void* d_out, int out_size, void* d_ws, size_t ws_size,
                              hipStream_t stream) {
  const float* feat       = (const float*)d_in[0];
  const int*   grid_coord = (const int*)d_in[1];
  const int*   order      = (const int*)d_in[2];
  const int*   inverse    = (const int*)d_in[3];
  const float* w_qkv      = (const float*)d_in[4];
  const float* b_qkv      = (const float*)d_in[5];
  const float* w_proj     = (const float*)d_in[6];
  const float* b_proj     = (const float*)d_in[7];
  float* out = (float*)d_out;

  char* ws = (char*)d_ws;
  bf16_t* Bt1   = (bf16_t*)(ws);                 // 2304x768  bf16
  bf16_t* Bt2   = (bf16_t*)(ws + 3538944);       // 768x768   bf16
  bf16_t* featp = (bf16_t*)(ws + 4718592);       // 32768x768 bf16
  bf16_t* Qb    = (bf16_t*)(ws + 55050240);      // 32768x768 bf16
  bf16_t* Kb    = (bf16_t*)(ws + 105381888);     // 32768x768 bf16
  bf16_t* Vt    = (bf16_t*)(ws + 155713536);     // 768x32768 bf16 (V transposed)
  float*  posf  = (float*)(ws + 206045184);      // 32768x3 fp32

  static bool attr_set = false;
  if (!attr_set) {
    (void)hipFuncSetAttribute((const void*)gemm256_k<0, 9>,
                              hipFuncAttributeMaxDynamicSharedMemorySize, 131072);
    (void)hipFuncSetAttribute((const void*)gemm_proj_k,
                              hipFuncAttributeMaxDynamicSharedMemorySize, 98304);
    (void)hipFuncSetAttribute((const void*)attn_k,
                              hipFuncAttributeMaxDynamicSharedMemorySize, 131072);
    attr_set = true;
  }

  transpose_cast_k<<<dim3(36, 12), 256, 0, stream>>>(w_qkv, Bt1, 768, 2304);
  transpose_cast_k<<<dim3(12, 12), 256, 0, stream>>>(w_proj, Bt2, 768, 768);
  gather_cast_k<<<24576, 256, 0, stream>>>(feat, order, grid_coord, featp, posf);
  gemm256_k<0, 9><<<1152, 512, 131072, stream>>>(featp, Bt1, b_qkv, Qb, Kb, Vt,
                                                 nullptr, nullptr, posf);
  attn_k<<<1024, 512, 131072, stream>>>(Qb, Kb, Vt);
  gemm_proj_k<<<768, 512, 98304, stream>>>(Qb, Bt2, b_proj, out, inverse);
}

// Round 7
// 474.852 us; speedup vs baseline: 1.0200x; 1.0080x over previous
//
#include <hip/hip_runtime.h>
#include <hip/hip_bf16.h>
#include <stdint.h>

typedef __bf16 bf16_t;
typedef __bf16 bf16x8 __attribute__((ext_vector_type(8)));
typedef __bf16 bf16x4 __attribute__((ext_vector_type(4)));
typedef float f32x4 __attribute__((ext_vector_type(4)));

template <int V> struct ic { static constexpr int value = V; };

// async global->LDS, 16B per lane. LDS dest must be wave-uniform base + lane*16;
// the GLOBAL source is per-lane (used to fold gathers/permutations into staging).
__device__ __forceinline__ void gload_lds16(const bf16_t* g, bf16_t* l) {
  __builtin_amdgcn_global_load_lds((const __attribute__((address_space(1))) void*)g,
                                   (__attribute__((address_space(3))) void*)l, 16, 0, 0);
}

// ---------------- fp32 W[k][m] -> bf16 Bt[m][k] (tiled transpose + cast) --------
__global__ __launch_bounds__(256) void transpose_cast_k(const float* __restrict__ W,
                                                        bf16_t* __restrict__ Bt,
                                                        int KDin, int MDin) {
  __shared__ float tile[64][65];
  const int bm = blockIdx.x, bk = blockIdx.y;
  const int c = threadIdx.x & 63, r0 = threadIdx.x >> 6;
#pragma unroll
  for (int rr = 0; rr < 16; ++rr) {
    int row = rr * 4 + r0;
    tile[row][c] = W[(size_t)(bk * 64 + row) * MDin + bm * 64 + c];
  }
  __syncthreads();
#pragma unroll
  for (int rr = 0; rr < 16; ++rr) {
    int mo = rr * 4 + r0;
    Bt[(size_t)(bm * 64 + mo) * KDin + bk * 64 + c] = (bf16_t)tile[c][mo];
  }
}

// ---------------- feat[order[j]] -> bf16 featp[j]; also emit posf[j][3] --------
__global__ __launch_bounds__(256) void gather_cast_k(const float* __restrict__ feat,
                                                     const int* __restrict__ order,
                                                     const int* __restrict__ grid_coord,
                                                     bf16_t* __restrict__ featp,
                                                     float* __restrict__ posf) {
  const int id = blockIdx.x * 256 + threadIdx.x;  // 32768*192 total
  const int j = id / 192;
  const int c = (id % 192) * 4;
  const int g = order[j];
  const float4 v = *(const float4*)(feat + (size_t)g * 768 + c);
  bf16x4 o;
  o[0] = (bf16_t)v.x; o[1] = (bf16_t)v.y; o[2] = (bf16_t)v.z; o[3] = (bf16_t)v.w;
  *(bf16x4*)(featp + (size_t)j * 768 + c) = o;
  if (c == 0) {
    posf[j * 3 + 0] = (float)grid_coord[g * 3 + 0];
    posf[j * 3 + 1] = (float)grid_coord[g * 3 + 1];
    posf[j * 3 + 2] = (float)grid_coord[g * 3 + 2];
  }
}

// ---------------- 256x256 GEMM, ONE 32-MFMA phase per K-tile -------------------
// C[j][m] = A[j][:].Bt[m][:]+bias.  K=768 = 24 K-tiles of BK=32, ring-4 LDS
// (A 16KB + B 16KB per tile, 128KB).  Per phase:
//   { ds_read af[8]+bfr[4] (12 b128, tile t; landing guaranteed by phase t-1's
//     vmcnt+barrier) | stage tile t+3 (4 loads) | vmcnt(8) (tile t+1 lands) |
//     barrier | lgkm0+sched_barrier | 32 MFMA (setprio) | barrier }
// Phase count per block: 24 (was 48) — halves the per-phase sync overhead that
// the r6 post-mortem identified as the binding constraint (~530cy/phase).
// MODE 0: bf16 stores into Cq/Ck (fused RoPE) and TRANSPOSED V into Cv=Vt.
// MODE 1: fp32 scatter (unused now).
template <int MODE, int NBX>
__global__ __launch_bounds__(512, 2) void gemm256_k(const bf16_t* __restrict__ A,
                                                    const bf16_t* __restrict__ Bt,
                                                    const float* __restrict__ bias,
                                                    bf16_t* __restrict__ Cq,
                                                    bf16_t* __restrict__ Ck,
                                                    bf16_t* __restrict__ Cv,
                                                    float* __restrict__ Cf,
                                                    const int* __restrict__ order,
                                                    const float* __restrict__ posf) {
  extern __shared__ bf16_t sm[];          // [4][8192] A bufs, then [4][8192] B bufs
  bf16_t* ldsA = sm;
  bf16_t* ldsB = sm + 4 * 8192;

  const int tid = threadIdx.x;
  const int lane = tid & 63, wave = tid >> 6;
  const int wr = wave >> 2, wc = wave & 3;  // 2 x 4 wave grid
  const int lq = lane & 15, lk = lane >> 4;

  const int bid = blockIdx.x;
  const int cpx = gridDim.x >> 3;         // gridDim.x % 8 == 0
  const int rm = (bid & 7) * cpx + (bid >> 3);
  const int by = rm / NBX, bx = rm % NBX;

  const int o0 = tid, o1 = tid + 512;
  const int r0s = o0 >> 2, ls0 = (o0 & 3) ^ ((r0s >> 1) & 3);
  const int r1s = o1 >> 2, ls1 = (o1 & 3) ^ ((r1s >> 1) & 3);
  const bf16_t* pA0 = A + (size_t)(by * 256 + r0s) * 768 + ls0 * 8;
  const bf16_t* pA1 = A + (size_t)(by * 256 + r1s) * 768 + ls1 * 8;
  const bf16_t* pB0 = Bt + (size_t)(bx * 256 + r0s) * 768 + ls0 * 8;
  const bf16_t* pB1 = Bt + (size_t)(bx * 256 + r1s) * 768 + ls1 * 8;

  auto stageAB = [&](int kt) {
    bf16_t* dA = ldsA + ((kt & 3) << 13);
    bf16_t* dB = ldsB + ((kt & 3) << 13);
    gload_lds16(pA0 + kt * 32, dA + o0 * 8);
    gload_lds16(pA1 + kt * 32, dA + o1 * 8);
    gload_lds16(pB0 + kt * 32, dB + o0 * 8);
    gload_lds16(pB1 + kt * 32, dB + o1 * 8);
  };

  const int pslot = lk ^ ((lq >> 1) & 3);

  f32x4 acc[8][4] = {};

  // ---- prologue: stage tiles 0,1,2 (12 loads); wait tile 0 (oldest 4)
  stageAB(0); stageAB(1); stageAB(2);
  asm volatile("s_waitcnt vmcnt(8)" ::: "memory");
  __builtin_amdgcn_s_barrier();
  __builtin_amdgcn_sched_barrier(0);

  auto phase = [&](int t, auto VMC, auto STGC) {
    constexpr int VM = decltype(VMC)::value;
    constexpr bool STG = decltype(STGC)::value;
    const bf16_t* Ab = ldsA + ((t & 3) << 13);
    const bf16_t* Bb = ldsB + ((t & 3) << 13);
    bf16x8 af[8], bfr[4];
#pragma unroll
    for (int m = 0; m < 8; ++m)
      af[m] = *(const bf16x8*)(Ab + (wr * 128 + m * 16 + lq) * 32 + pslot * 8);
#pragma unroll
    for (int n = 0; n < 4; ++n)
      bfr[n] = *(const bf16x8*)(Bb + (wc * 64 + n * 16 + lq) * 32 + pslot * 8);
    if constexpr (STG) stageAB(t + 3);
    if constexpr (VM == 8) asm volatile("s_waitcnt vmcnt(8)" ::: "memory");
    else if constexpr (VM == 4) asm volatile("s_waitcnt vmcnt(4)" ::: "memory");
    else if constexpr (VM == 0) asm volatile("s_waitcnt vmcnt(0)" ::: "memory");
    __builtin_amdgcn_s_barrier();
    asm volatile("s_waitcnt lgkmcnt(0)" ::: "memory");
    __builtin_amdgcn_sched_barrier(0);
    __builtin_amdgcn_s_setprio(1);
#pragma unroll
    for (int n = 0; n < 4; ++n)
#pragma unroll
      for (int m = 0; m < 8; ++m)
        acc[m][n] = __builtin_amdgcn_mfma_f32_16x16x32_bf16(af[m], bfr[n], acc[m][n], 0, 0, 0);
    __builtin_amdgcn_s_setprio(0);
    __builtin_amdgcn_s_barrier();
    __builtin_amdgcn_sched_barrier(0);
  };

  for (int t = 0; t < 21; ++t) phase(t, ic<8>{}, ic<1>{});
  phase(21, ic<4>{}, ic<0>{});
  phase(22, ic<0>{}, ic<0>{});
  phase(23, ic<-1>{}, ic<0>{});

  // ---- epilogue ----
  const int colb = bx * 256 + wc * 64;
  float bcol[4];
#pragma unroll
  for (int n = 0; n < 4; ++n) bcol[n] = bias[colb + n * 16 + lq];

  if (MODE == 0) {
    const int sec = bx / 3;               // 0=Q, 1=K, 2=V  (NBX==9, 768%256==0)
    const int coll = colb - sec * 768;
    if (sec < 2) {
      bf16_t* base = sec == 0 ? Cq : Ck;
      const int a0 = (colb % 96) >> 5;
      const int a1 = ((colb + 32) % 96) >> 5;
      const float fr = exp2f(-0.41524101186f * (float)lq);  // 100^(-lq/16)
#pragma unroll
      for (int m = 0; m < 8; ++m) {
        const int rowb = by * 256 + wr * 128 + m * 16 + lk * 4;
#pragma unroll
        for (int r = 0; r < 4; ++r) {
          const int row = rowb + r;
          float s0, c0, s1, c1;
          __sincosf(posf[row * 3 + a0] * fr, &s0, &c0);
          __sincosf(posf[row * 3 + a1] * fr, &s1, &c1);
          const float x1 = acc[m][0][r] + bcol[0], x2 = acc[m][1][r] + bcol[1];
          const float y1 = acc[m][2][r] + bcol[2], y2 = acc[m][3][r] + bcol[3];
          acc[m][0][r] = x1 * c0 - x2 * s0;
          acc[m][1][r] = x1 * s0 + x2 * c0;
          acc[m][2][r] = y1 * c1 - y2 * s1;
          acc[m][3][r] = y1 * s1 + y2 * c1;
        }
#pragma unroll
        for (int n = 0; n < 4; ++n) {
          const int col = coll + n * 16 + lq;
#pragma unroll
          for (int r = 0; r < 4; ++r)
            base[(size_t)(rowb + r) * 768 + col] = (bf16_t)acc[m][n][r];
        }
      }
    } else {
      // V: store TRANSPOSED -> Cv = Vt[feat][token].
#pragma unroll
      for (int m = 0; m < 8; ++m) {
        const int rowb = by * 256 + wr * 128 + m * 16 + lk * 4;
#pragma unroll
        for (int n = 0; n < 4; ++n) {
          const int col = coll + n * 16 + lq;
          bf16x4 o;
#pragma unroll
          for (int r = 0; r < 4; ++r) o[r] = (bf16_t)(acc[m][n][r] + bcol[n]);
          *(bf16x4*)(Cv + (size_t)col * 32768 + rowb) = o;
        }
      }
    }
  } else {
#pragma unroll
    for (int m = 0; m < 8; ++m) {
      const int rowb = by * 256 + wr * 128 + m * 16 + lk * 4;
      int ro[4];
#pragma unroll
      for (int r = 0; r < 4; ++r) ro[r] = order[rowb + r];
#pragma unroll
      for (int n = 0; n < 4; ++n) {
        const int col = colb + n * 16 + lq;
#pragma unroll
        for (int r = 0; r < 4; ++r)
          Cf[(size_t)ro[r] * 768 + col] = acc[m][n][r] + bcol[n];
      }
    }
  }
}

// ---------------- projection GEMM: out[i] = Qb[inverse[i]].Bt2 + bias ----------
// BM=128 x BN=256, grid 768 (= 3 rounds).  TWO K-tiles per phase (32 MFMA,
// 16 b128), pair-granular ring-4 (96KB): phase p stages pair p+1 (6 loads),
// vmcnt(6) lands pair p, barrier, ds_read both tiles, lgkm0, 32 MFMA, barrier.
// 12 phases per block (was 24).  A-rows gathered through inverse[] in the
// per-lane global source; C-writes dense coalesced fp32.
__global__ __launch_bounds__(512, 2) void gemm_proj_k(const bf16_t* __restrict__ A,
                                                      const bf16_t* __restrict__ Bt,
                                                      const float* __restrict__ bias,
                                                      float* __restrict__ Cf,
                                                      const int* __restrict__ inverse) {
  extern __shared__ bf16_t sm[];
  bf16_t* ldsA = sm;            // 4 slots x 4096 bf16 (8KB)  = 32KB
  bf16_t* ldsB = sm + 16384;    // 4 slots x 8192 bf16 (16KB) = 64KB

  const int tid = threadIdx.x;
  const int lane = tid & 63, wave = tid >> 6;
  const int wr = wave >> 2, wc = wave & 3;  // 2 x 4 wave grid
  const int lq = lane & 15, lk = lane >> 4;

  const int bid = blockIdx.x;
  const int cpx = gridDim.x >> 3;           // 768/8 = 96
  const int rm = (bid & 7) * cpx + (bid >> 3);
  const int by = rm / 3, bx = rm % 3;

  const int rA = tid >> 2, lsA = (tid & 3) ^ ((rA >> 1) & 3);
  const int gA = inverse[by * 128 + rA];
  const bf16_t* pA = A + (size_t)gA * 768 + lsA * 8;
  const int o0 = tid, o1 = tid + 512;
  const int rB0 = o0 >> 2, lsB0 = (o0 & 3) ^ ((rB0 >> 1) & 3);
  const int rB1 = o1 >> 2, lsB1 = (o1 & 3) ^ ((rB1 >> 1) & 3);
  const bf16_t* pB0 = Bt + (size_t)(bx * 256 + rB0) * 768 + lsB0 * 8;
  const bf16_t* pB1 = Bt + (size_t)(bx * 256 + rB1) * 768 + lsB1 * 8;

  auto stage = [&](int kt) {
    const int slot = kt & 3;
    gload_lds16(pA + kt * 32, ldsA + (slot << 12) + tid * 8);
    gload_lds16(pB0 + kt * 32, ldsB + (slot << 13) + o0 * 8);
    gload_lds16(pB1 + kt * 32, ldsB + (slot << 13) + o1 * 8);
  };

  const int pslot = lk ^ ((lq >> 1) & 3);

  f32x4 acc[4][4] = {};

  // prologue: pair 0 (tiles 0,1) in flight.
  stage(0); stage(1);

  auto phasep = [&](int p, auto VMC, auto STGC) {
    constexpr int VM = decltype(VMC)::value;
    constexpr bool STG = decltype(STGC)::value;
    if constexpr (STG) { stage(2 * p + 2); stage(2 * p + 3); }
    if constexpr (VM == 6) asm volatile("s_waitcnt vmcnt(6)" ::: "memory");
    else if constexpr (VM == 0) asm volatile("s_waitcnt vmcnt(0)" ::: "memory");
    __builtin_amdgcn_s_barrier();
    bf16x8 af[2][4], bfr[2][4];
#pragma unroll
    for (int hh = 0; hh < 2; ++hh) {
      const int kt = 2 * p + hh;
      const bf16_t* Ab = ldsA + ((kt & 3) << 12);
      const bf16_t* Bb = ldsB + ((kt & 3) << 13);
#pragma unroll
      for (int m = 0; m < 4; ++m)
        af[hh][m] = *(const bf16x8*)(Ab + (wr * 64 + m * 16 + lq) * 32 + pslot * 8);
#pragma unroll
      for (int n = 0; n < 4; ++n)
        bfr[hh][n] = *(const bf16x8*)(Bb + (wc * 64 + n * 16 + lq) * 32 + pslot * 8);
    }
    asm volatile("s_waitcnt lgkmcnt(0)" ::: "memory");
    __builtin_amdgcn_sched_barrier(0);
    __builtin_amdgcn_s_setprio(1);
#pragma unroll
    for (int hh = 0; hh < 2; ++hh)
#pragma unroll
      for (int n = 0; n < 4; ++n)
#pragma unroll
        for (int m = 0; m < 4; ++m)
          acc[m][n] = __builtin_amdgcn_mfma_f32_16x16x32_bf16(af[hh][m], bfr[hh][n], acc[m][n], 0, 0, 0);
    __builtin_amdgcn_s_setprio(0);
    __builtin_amdgcn_s_barrier();
    __builtin_amdgcn_sched_barrier(0);
  };

  for (int p = 0; p < 11; ++p) phasep(p, ic<6>{}, ic<1>{});
  phasep(11, ic<0>{}, ic<0>{});

  // ---- epilogue: dense coalesced fp32 rows in ORIGINAL order ----
  const int colb = bx * 256 + wc * 64;
  float bcol[4];
#pragma unroll
  for (int n = 0; n < 4; ++n) bcol[n] = bias[colb + n * 16 + lq];
#pragma unroll
  for (int m = 0; m < 4; ++m) {
    const int rowb = by * 128 + wr * 64 + m * 16 + lk * 4;
#pragma unroll
    for (int n = 0; n < 4; ++n) {
      const int col = colb + n * 16 + lq;
#pragma unroll
      for (int r = 0; r < 4; ++r)
        Cf[(size_t)(rowb + r) * 768 + col] = acc[m][n][r] + bcol[n];
    }
  }
}

// ---------------- windowed attention v5: one block per (p,h), 8 waves ----------
// (unchanged from round 6)
__global__ __launch_bounds__(512) void attn_k(bf16_t* QO,   // Q in, O out (same buffer)
                                              const bf16_t* __restrict__ Kb,
                                              const bf16_t* __restrict__ Vt) {
  extern __shared__ bf16_t alds[];
  bf16_t* Kreg = alds;            // 24576 bf16 (48KB)
  bf16_t* Vreg = alds + 24576;    // 24576 bf16 (48KB)
  const int bid = blockIdx.x;
  const int h = bid & 7, p = bid >> 3;
  const int tid = threadIdx.x, lane = tid & 63, wave = tid >> 6;
  const int lq = lane & 15, lk = lane >> 4;
  const int tok0 = p * 256;
  const float scale = 0.10206207262f;  // 96^-0.5
  bf16_t* pw = alds + 49152 + wave * 2048;  // per-wave 16x128 swizzled P half

  // ---- Q -> regs first (so vmcnt(6) below covers them) ----
  bf16x8 aq[2][3];
#pragma unroll
  for (int rb = 0; rb < 2; ++rb) {
    const bf16_t* qb = QO + (size_t)(tok0 + wave * 32 + rb * 16 + lq) * 768 + h * 96 + lk * 8;
#pragma unroll
    for (int kc = 0; kc < 3; ++kc) aq[rb][kc] = *(const bf16x8*)(qb + kc * 32);
  }
  __builtin_amdgcn_sched_barrier(0);   // pin Q-load issue before K/V staging

  // ---- stage K frags (6 x 512 chunks), straight from row-major Kb.
#pragma unroll
  for (int i = 0; i < 6; ++i) {
    const int fi = i * 8 + wave;
    const int nt = fi / 3, a = fi - nt * 3;
    const bf16_t* src = Kb + (size_t)(tok0 + nt * 16 + (lane & 15)) * 768 +
                        h * 96 + a * 32 + (lane >> 4) * 8;
    gload_lds16(src, Kreg + i * 4096 + tid * 8);
  }
  // ---- stage V frags from transposed Vt[feat][token].
#pragma unroll
  for (int i = 0; i < 6; ++i) {
    const int fi = i * 8 + wave;
    const int d = (fi >> 3) * 16 + (lane & 15);
    const int tb = (fi & 7) * 32 + (lane >> 4) * 8;
    const bf16_t* src = Vt + (size_t)(h * 96 + d) * 32768 + tok0 + tb;
    gload_lds16(src, Vreg + i * 4096 + tid * 8);
  }

  asm volatile("s_waitcnt vmcnt(6)" ::: "memory");   // Q + K complete
  __builtin_amdgcn_s_barrier();

#pragma unroll
  for (int rb = 0; rb < 2; ++rb) {
    // ---- S = Q.K^T from LDS
    f32x4 sacc[16];
#pragma unroll
    for (int nt = 0; nt < 16; ++nt) {
      f32x4 acc = {0.f, 0.f, 0.f, 0.f};
#pragma unroll
      for (int kc = 0; kc < 3; ++kc) {
        bf16x8 bk = *(const bf16x8*)(Kreg + (size_t)((nt * 3 + kc) * 64 + lane) * 8);
        acc = __builtin_amdgcn_mfma_f32_16x16x32_bf16(aq[rb][kc], bk, acc, 0, 0, 0);
      }
      sacc[nt] = acc;
    }

    // ---- softmax (rows in C-layout: row = lk*4+r, col = nt*16+lq)
    float linv[4];
#pragma unroll
    for (int r = 0; r < 4; ++r) {
      float mx = -1e30f;
#pragma unroll
      for (int nt = 0; nt < 16; ++nt) mx = fmaxf(mx, sacc[nt][r]);
      mx = fmaxf(mx, __shfl_xor(mx, 1));
      mx = fmaxf(mx, __shfl_xor(mx, 2));
      mx = fmaxf(mx, __shfl_xor(mx, 4));
      mx = fmaxf(mx, __shfl_xor(mx, 8));
      mx *= scale;
      float l = 0.f;
#pragma unroll
      for (int nt = 0; nt < 16; ++nt) {
        float e = __expf(sacc[nt][r] * scale - mx);
        sacc[nt][r] = e;
        l += e;
      }
      l += __shfl_xor(l, 1);
      l += __shfl_xor(l, 2);
      l += __shfl_xor(l, 4);
      l += __shfl_xor(l, 8);
      linv[r] = 1.f / l;
    }

    if (rb == 0) {
      asm volatile("s_waitcnt vmcnt(0)" ::: "memory");  // V staged (all waves)
      __builtin_amdgcn_s_barrier();
    }

    // ---- PV in two 128-token halves through private swizzled P buffer.
    f32x4 oacc[6] = {};
#pragma unroll
    for (int hf = 0; hf < 2; ++hf) {
#pragma unroll
      for (int ntl = 0; ntl < 8; ++ntl) {
        const int nt = hf * 8 + ntl;
        const int chk = ntl * 2 + (lq >> 3);
#pragma unroll
        for (int r = 0; r < 4; ++r) {
          const int row = lk * 4 + r;
          const int phys = chk ^ (row & 7);
          pw[row * 128 + phys * 8 + (lq & 7)] = (bf16_t)sacc[nt][r];
        }
      }
#pragma unroll
      for (int kcl = 0; kcl < 4; ++kcl) {
        const int physr = (kcl * 4 + lk) ^ (lq & 7);
        bf16x8 pf = *(const bf16x8*)(pw + lq * 128 + physr * 8);
        const int kc = hf * 4 + kcl;
#pragma unroll
        for (int dt = 0; dt < 6; ++dt) {
          bf16x8 vb = *(const bf16x8*)(Vreg + (size_t)((dt * 8 + kc) * 64 + lane) * 8);
          oacc[dt] = __builtin_amdgcn_mfma_f32_16x16x32_bf16(pf, vb, oacc[dt], 0, 0, 0);
        }
      }
    }

    // ---- write O over Q (all global Q loads completed at the rb0 barrier)
#pragma unroll
    for (int dt = 0; dt < 6; ++dt) {
#pragma unroll
      for (int r = 0; r < 4; ++r) {
        const int row = tok0 + wave * 32 + rb * 16 + lk * 4 + r;
        QO[(size_t)row * 768 + h * 96 + dt * 16 + lq] = (bf16_t)(oacc[dt][r] * linv[r]);
      }
    }
  }
}

extern "C" void kernel_launch(void* const* d_in, const int* in_sizes, int n_in,
                              void* d_out, int out_size, void* d_ws, size_t ws_size,
                              hipStream_t stream) {
  const float* feat       = (const float*)d_in[0];
  const int*   grid_coord = (const int*)d_in[1];
  const int*   order      = (const int*)d_in[2];
  const int*   inverse    = (const int*)d_in[3];
  const float* w_qkv      = (const float*)d_in[4];
  const float* b_qkv      = (const float*)d_in[5];
  const float* w_proj     = (const float*)d_in[6];
  const float* b_proj     = (const float*)d_in[7];
  float* out = (float*)d_out;

  char* ws = (char*)d_ws;
  bf16_t* Bt1   = (bf16_t*)(ws);                 // 2304x768  bf16
  bf16_t* Bt2   = (bf16_t*)(ws + 3538944);       // 768x768   bf16
  bf16_t* featp = (bf16_t*)(ws + 4718592);       // 32768x768 bf16
  bf16_t* Qb    = (bf16_t*)(ws + 55050240);      // 32768x768 bf16
  bf16_t* Kb    = (bf16_t*)(ws + 105381888);     // 32768x768 bf16
  bf16_t* Vt    = (bf16_t*)(ws + 155713536);     // 768x32768 bf16 (V transposed)
  float*  posf  = (float*)(ws + 206045184);      // 32768x3 fp32

  static bool attr_set = false;
  if (!attr_set) {
    (void)hipFuncSetAttribute((const void*)gemm256_k<0, 9>,
                              hipFuncAttributeMaxDynamicSharedMemorySize, 131072);
    (void)hipFuncSetAttribute((const void*)gemm_proj_k,
                              hipFuncAttributeMaxDynamicSharedMemorySize, 98304);
    (void)hipFuncSetAttribute((const void*)attn_k,
                              hipFuncAttributeMaxDynamicSharedMemorySize, 131072);
    attr_set = true;
  }

  transpose_cast_k<<<dim3(36, 12), 256, 0, stream>>>(w_qkv, Bt1, 768, 2304);
  transpose_cast_k<<<dim3(12, 12), 256, 0, stream>>>(w_proj, Bt2, 768, 768);
  gather_cast_k<<<24576, 256, 0, stream>>>(feat, order, grid_coord, featp, posf);
  gemm256_k<0, 9><<<1152, 512, 131072, stream>>>(featp, Bt1, b_qkv, Qb, Kb, Vt,
                                                 nullptr, nullptr, posf);
  attn_k<<<1024, 512, 131072, stream>>>(Qb, Kb, Vt);
  gemm_proj_k<<<768, 512, 98304, stream>>>(Qb, Bt2, b_proj, out, inverse);
}